// Round 3
// baseline (829.593 us; speedup 1.0000x reference)
//
#include <hip/hip_runtime.h>

#define AREA 4096

// ---------------- pointwise channel projection -------------------------
// acc over Cin; weights read via wave-uniform (scalar) loads.
// TRANSP: out[((n*12+gy)*A + a)*pstr + voff + oo]   (gather-major for q/k/v)
// else:   out[n*out_n_stride + (gy*TO+oo)*A + a]    (channel-major)
template<int TO, bool GELU, bool RES, bool TRANSP>
__global__ __launch_bounds__(256) void proj_kernel(
    const float* __restrict__ in, const float* __restrict__ Wm,
    const float* __restrict__ bias, float* __restrict__ out,
    const float* __restrict__ res,
    int Cin, long in_stride, long out_n_stride, int pstr, int voff)
{
    const int tid = threadIdx.x;
    const int a = blockIdx.x * 256 + tid;
    const int gy = blockIdx.y;
    const int n = blockIdx.z;
    const float* __restrict__ inp = in + (long)n * in_stride + a;
    const float* __restrict__ wp = Wm + (long)gy * TO * Cin;

    float acc[TO];
#pragma unroll
    for (int i = 0; i < TO; ++i) acc[i] = 0.f;

    const int CH = 8;
    for (int c0 = 0; c0 < Cin; c0 += CH) {
        float xv[CH];
#pragma unroll
        for (int cc = 0; cc < CH; ++cc)
            xv[cc] = inp[(long)(c0 + cc) * AREA];
#pragma unroll
        for (int oo = 0; oo < TO; ++oo) {
            const float* wrow = wp + (long)oo * Cin + c0;   // wave-uniform -> s_load
#pragma unroll
            for (int cc = 0; cc < CH; ++cc)
                acc[oo] = fmaf(wrow[cc], xv[cc], acc[oo]);
        }
    }

    if (TRANSP) {
        float* ob = out + ((long)(n * 12 + gy) * AREA + a) * pstr + voff;
#pragma unroll
        for (int oo = 0; oo < TO; ++oo)
            ob[oo] = acc[oo] + bias[gy * TO + oo];
    } else {
        const long obase = (long)n * out_n_stride;
#pragma unroll
        for (int oo = 0; oo < TO; ++oo) {
            float vr = acc[oo] + bias[gy * TO + oo];
            if (GELU) vr = 0.5f * vr * (1.f + erff(vr * 0.70710678118654752f));
            long addr = obase + (long)(gy * TO + oo) * AREA + a;
            if (RES) vr += res[addr];
            out[addr] = vr;
        }
    }
}

// ---------------- deformable attention ---------------------------------
// qp_t: (B*12, A, 24)    kv_t: (B*CLIP*12, A, 48)  [0:24]=K [24:48]=V
// offs: (B, 432, A)      o:    (B, 288, A)
// 2 threads per (b,g,a) site: half = lane&1 handles 12 channels.
__global__ __launch_bounds__(256) void deform_attn_kernel(
    const float* __restrict__ qp, const float* __restrict__ kv,
    const float* __restrict__ offs, float* __restrict__ o)
{
    const int t = blockIdx.x * 256 + threadIdx.x;
    const int half = t & 1;
    const int site = t >> 1;                 // b*12*A + g*A + a
    const int a = site & (AREA - 1);
    const int g = (site >> 12) % 12;
    const int b = site / (12 * AREA);
    const int py = a >> 6;
    const int px = a & 63;
    const int h12 = half * 12;
    const float scale = 0.20412414523193150818f;   // 1/sqrt(24)

    float qv[12];
    {
        const float4* qb = (const float4*)(qp + ((long)(b * 12 + g) * AREA + a) * 24 + h12);
        float4 q0 = qb[0], q1 = qb[1], q2 = qb[2];
        qv[0]=q0.x*scale; qv[1]=q0.y*scale; qv[2]=q0.z*scale; qv[3]=q0.w*scale;
        qv[4]=q1.x*scale; qv[5]=q1.y*scale; qv[6]=q1.z*scale; qv[7]=q1.w*scale;
        qv[8]=q2.x*scale; qv[9]=q2.y*scale; qv[10]=q2.z*scale; qv[11]=q2.w*scale;
    }

    float m = -1e30f, l = 0.f;
    float outv[12];
#pragma unroll
    for (int d = 0; d < 12; ++d) outv[d] = 0.f;

    for (int clip = 0; clip < 2; ++clip) {
        const float* __restrict__ cb = kv + (long)((b * 2 + clip) * 12 + g) * AREA * 48;
        const float* __restrict__ obase = offs + ((long)b * 432 + (clip * 12 + g) * 18) * AREA;
#pragma unroll 1
        for (int k = 0; k < 9; ++k) {
            float oy = obase[(long)(2 * k) * AREA + a];
            float ox = obase[(long)(2 * k + 1) * AREA + a];
            int ky = k / 3, kx = k - ky * 3;
            float ys = (float)(py + ky - 1) + oy;
            float xs = (float)(px + kx - 1) + ox;
            float y0f = floorf(ys), x0f = floorf(xs);
            float dy = ys - y0f, dx = xs - x0f;
            float wy[2] = {1.f - dy, dy};
            float wx[2] = {1.f - dx, dx};
            long  idx4[4];
            float w4[4];
#pragma unroll
            for (int cy = 0; cy < 2; ++cy) {
                float yc = y0f + (float)cy;
                bool vy = (yc >= 0.f) && (yc <= 63.f);
                int yi = (int)fminf(fmaxf(yc, 0.f), 63.f);
#pragma unroll
                for (int cx = 0; cx < 2; ++cx) {
                    float xc = x0f + (float)cx;
                    bool vx = (xc >= 0.f) && (xc <= 63.f);
                    int xi = (int)fminf(fmaxf(xc, 0.f), 63.f);
                    w4[cy * 2 + cx] = wy[cy] * wx[cx] * ((vy && vx) ? 1.f : 0.f);
                    idx4[cy * 2 + cx] = (long)(yi * 64 + xi) * 48;
                }
            }
            // ---- logit: dot per corner, then weight ----
            float sh = 0.f;
#pragma unroll
            for (int c = 0; c < 4; ++c) {
                const float4* kc = (const float4*)(cb + idx4[c] + h12);
                float4 k0 = kc[0], k1 = kc[1], k2 = kc[2];
                float d = qv[0]*k0.x + qv[1]*k0.y + qv[2]*k0.z + qv[3]*k0.w
                        + qv[4]*k1.x + qv[5]*k1.y + qv[6]*k1.z + qv[7]*k1.w
                        + qv[8]*k2.x + qv[9]*k2.y + qv[10]*k2.z + qv[11]*k2.w;
                sh = fmaf(w4[c], d, sh);
            }
            float s = sh + __shfl_xor(sh, 1);
            // ---- online softmax ----
            float mn = fmaxf(m, s);
            float corr = __expf(m - mn);
            float p = __expf(s - mn);
            l = l * corr + p;
            m = mn;
            // ---- V sample + accumulate ----
            float vs[12];
#pragma unroll
            for (int d = 0; d < 12; ++d) vs[d] = 0.f;
#pragma unroll
            for (int c = 0; c < 4; ++c) {
                const float4* vc = (const float4*)(cb + idx4[c] + 24 + h12);
                float4 v0 = vc[0], v1 = vc[1], v2 = vc[2];
                float w = w4[c];
                vs[0] = fmaf(w, v0.x, vs[0]);  vs[1] = fmaf(w, v0.y, vs[1]);
                vs[2] = fmaf(w, v0.z, vs[2]);  vs[3] = fmaf(w, v0.w, vs[3]);
                vs[4] = fmaf(w, v1.x, vs[4]);  vs[5] = fmaf(w, v1.y, vs[5]);
                vs[6] = fmaf(w, v1.z, vs[6]);  vs[7] = fmaf(w, v1.w, vs[7]);
                vs[8] = fmaf(w, v2.x, vs[8]);  vs[9] = fmaf(w, v2.y, vs[9]);
                vs[10] = fmaf(w, v2.z, vs[10]); vs[11] = fmaf(w, v2.w, vs[11]);
            }
#pragma unroll
            for (int d = 0; d < 12; ++d)
                outv[d] = fmaf(outv[d], corr, p * vs[d]);
        }
    }
    float inv = 1.f / l;
#pragma unroll
    for (int d = 0; d < 12; ++d)
        o[((long)b * 288 + g * 24 + h12 + d) * AREA + a] = outv[d] * inv;
}

extern "C" void kernel_launch(void* const* d_in, const int* in_sizes, int n_in,
                              void* d_out, int out_size, void* d_ws, size_t ws_size,
                              hipStream_t stream) {
    const float* q      = (const float*)d_in[0];
    const float* k      = (const float*)d_in[1];
    const float* v      = (const float*)d_in[2];
    const float* offset = (const float*)d_in[3];
    const float* Wq     = (const float*)d_in[4];
    const float* bq     = (const float*)d_in[5];
    const float* Wk     = (const float*)d_in[6];
    const float* bk     = (const float*)d_in[7];
    const float* Wv     = (const float*)d_in[8];
    const float* bv     = (const float*)d_in[9];
    const float* W1     = (const float*)d_in[10];
    const float* b1     = (const float*)d_in[11];
    const float* W2     = (const float*)d_in[12];
    const float* b2     = (const float*)d_in[13];
    float* out = (float*)d_out;
    float* ws  = (float*)d_ws;

    float* qp_t = ws;                      // B*12*A*24   = 2,359,296 floats
    float* kv_t = ws + 2359296;            // B*2*12*A*48 = 9,437,184 floats
    float* x1   = ws + 2359296;            // aliases kv_t after attention (2*576*A)

    dim3 blk(256);
    // q projection -> qp_t (gather-major, pstr=24)
    proj_kernel<24, false, false, true><<<dim3(16, 12, 2), blk, 0, stream>>>(
        q, Wq, bq, qp_t, nullptr, 288, 288L * AREA, 0, 24, 0);
    // k projection -> kv_t[..., 0:24]
    proj_kernel<24, false, false, true><<<dim3(16, 12, 4), blk, 0, stream>>>(
        k, Wk, bk, kv_t, nullptr, 288, 288L * AREA, 0, 48, 0);
    // v projection -> kv_t[..., 24:48]
    proj_kernel<24, false, false, true><<<dim3(16, 12, 4), blk, 0, stream>>>(
        v, Wv, bv, kv_t, nullptr, 288, 288L * AREA, 0, 48, 24);
    // deformable attention -> out ("o")
    deform_attn_kernel<<<dim3(768), blk, 0, stream>>>(qp_t, kv_t, offset, out);
    // FFN layer 1: out(288) -> x1(576) channel-major, GELU
    proj_kernel<24, true, false, false><<<dim3(16, 24, 2), blk, 0, stream>>>(
        out, W1, b1, x1, nullptr, 288, 288L * AREA, 576L * AREA, 0, 0);
    // FFN layer 2: x1(576) -> out(288) + residual o (in-place, same element)
    proj_kernel<24, false, true, false><<<dim3(16, 12, 2), blk, 0, stream>>>(
        x1, W2, b2, out, out, 576, 576L * AREA, 288L * AREA, 0, 0);
}

// Round 4
// 692.375 us; speedup vs baseline: 1.1982x; 1.1982x over previous
//
#include <hip/hip_runtime.h>

#define AREA 4096

// ---------------- pointwise channel projection -------------------------
// Register-tiled: TO out-channels x P pixels per thread.
// Weights staged in LDS per 8-channel step; read to regs via float4 broadcast.
// TRANSP: out[((n*12+gy)*A + a)*pstr + voff + oo]   (gather-major for q/k/v)
// else:   out[n*out_n_stride + (gy*TO+oo)*A + a]    (channel-major)
template<int TO, int P, bool GELU, bool RES, bool TRANSP>
__global__ __launch_bounds__(256) void proj_kernel(
    const float* __restrict__ in, const float* __restrict__ Wm,
    const float* __restrict__ bias, float* __restrict__ out,
    const float* __restrict__ res,
    int Cin, long in_stride, long out_n_stride, int pstr, int voff)
{
    const int CH = 8;
    __shared__ float wt[CH][TO];
    const int tid = threadIdx.x;
    const int a0 = blockIdx.x * (256 * P) + tid;
    const int gy = blockIdx.y;
    const int n  = blockIdx.z;
    const float* __restrict__ inp = in + (long)n * in_stride + a0;

    float acc[P][TO];
#pragma unroll
    for (int p = 0; p < P; ++p)
#pragma unroll
        for (int i = 0; i < TO; ++i) acc[p][i] = 0.f;

    for (int c0 = 0; c0 < Cin; c0 += CH) {
        __syncthreads();
        if (tid < CH * TO) {
            int cc = tid & 7;           // 8 consecutive tids read 8 consecutive c
            int oo = tid >> 3;
            wt[cc][oo] = Wm[(long)(gy * TO + oo) * Cin + c0 + cc];
        }
        __syncthreads();
        float xv[P][CH];
#pragma unroll
        for (int p = 0; p < P; ++p)
#pragma unroll
            for (int cc = 0; cc < CH; ++cc)
                xv[p][cc] = inp[(long)(c0 + cc) * AREA + p * 256];
#pragma unroll
        for (int cc = 0; cc < CH; ++cc) {
            const float4* wr = (const float4*)&wt[cc][0];   // 96B row, 16B aligned
            float wreg[TO];
#pragma unroll
            for (int i = 0; i < TO / 4; ++i) {
                float4 w = wr[i];
                wreg[4 * i + 0] = w.x; wreg[4 * i + 1] = w.y;
                wreg[4 * i + 2] = w.z; wreg[4 * i + 3] = w.w;
            }
#pragma unroll
            for (int oo = 0; oo < TO; ++oo)
#pragma unroll
                for (int p = 0; p < P; ++p)
                    acc[p][oo] = fmaf(wreg[oo], xv[p][cc], acc[p][oo]);
        }
    }

    if (TRANSP) {
#pragma unroll
        for (int p = 0; p < P; ++p) {
            float* ob = out + ((long)(n * 12 + gy) * AREA + (a0 + p * 256)) * pstr + voff;
#pragma unroll
            for (int oo = 0; oo < TO; ++oo)
                ob[oo] = acc[p][oo] + bias[gy * TO + oo];
        }
    } else {
        const long obase = (long)n * out_n_stride + a0;
#pragma unroll
        for (int oo = 0; oo < TO; ++oo) {
            float bi = bias[gy * TO + oo];
#pragma unroll
            for (int p = 0; p < P; ++p) {
                float vr = acc[p][oo] + bi;
                if (GELU) vr = 0.5f * vr * (1.f + erff(vr * 0.70710678118654752f));
                long addr = obase + (long)(gy * TO + oo) * AREA + p * 256;
                if (RES) vr += res[addr];
                out[addr] = vr;
            }
        }
    }
}

// ---------------- deformable attention ---------------------------------
// qp_t: (B*12, A, 24)    kv_t: (B*CLIP*12, A, 48)  [0:24]=K [24:48]=V
// offs: (B, 432, A)      o:    (B, 288, A)
// 2 threads per (b,g,a) site: half = lane&1 handles 12 channels.
__global__ __launch_bounds__(256) void deform_attn_kernel(
    const float* __restrict__ qp, const float* __restrict__ kv,
    const float* __restrict__ offs, float* __restrict__ o)
{
    const int t = blockIdx.x * 256 + threadIdx.x;
    const int half = t & 1;
    const int site = t >> 1;                 // b*12*A + g*A + a
    const int a = site & (AREA - 1);
    const int g = (site >> 12) % 12;
    const int b = site / (12 * AREA);
    const int py = a >> 6;
    const int px = a & 63;
    const int h12 = half * 12;
    const float scale = 0.20412414523193150818f;   // 1/sqrt(24)

    float qv[12];
    {
        const float4* qb = (const float4*)(qp + ((long)(b * 12 + g) * AREA + a) * 24 + h12);
        float4 q0 = qb[0], q1 = qb[1], q2 = qb[2];
        qv[0]=q0.x*scale; qv[1]=q0.y*scale; qv[2]=q0.z*scale; qv[3]=q0.w*scale;
        qv[4]=q1.x*scale; qv[5]=q1.y*scale; qv[6]=q1.z*scale; qv[7]=q1.w*scale;
        qv[8]=q2.x*scale; qv[9]=q2.y*scale; qv[10]=q2.z*scale; qv[11]=q2.w*scale;
    }

    float m = -1e30f, l = 0.f;
    float outv[12];
#pragma unroll
    for (int d = 0; d < 12; ++d) outv[d] = 0.f;

    for (int clip = 0; clip < 2; ++clip) {
        const float* __restrict__ cb = kv + (long)((b * 2 + clip) * 12 + g) * AREA * 48;
        const float* __restrict__ obase = offs + ((long)b * 432 + (clip * 12 + g) * 18) * AREA;
#pragma unroll 1
        for (int k = 0; k < 9; ++k) {
            float oy = obase[(long)(2 * k) * AREA + a];
            float ox = obase[(long)(2 * k + 1) * AREA + a];
            int ky = k / 3, kx = k - ky * 3;
            float ys = (float)(py + ky - 1) + oy;
            float xs = (float)(px + kx - 1) + ox;
            float y0f = floorf(ys), x0f = floorf(xs);
            float dy = ys - y0f, dx = xs - x0f;
            float wy[2] = {1.f - dy, dy};
            float wx[2] = {1.f - dx, dx};
            long  idx4[4];
            float w4[4];
#pragma unroll
            for (int cy = 0; cy < 2; ++cy) {
                float yc = y0f + (float)cy;
                bool vy = (yc >= 0.f) && (yc <= 63.f);
                int yi = (int)fminf(fmaxf(yc, 0.f), 63.f);
#pragma unroll
                for (int cx = 0; cx < 2; ++cx) {
                    float xc = x0f + (float)cx;
                    bool vx = (xc >= 0.f) && (xc <= 63.f);
                    int xi = (int)fminf(fmaxf(xc, 0.f), 63.f);
                    w4[cy * 2 + cx] = wy[cy] * wx[cx] * ((vy && vx) ? 1.f : 0.f);
                    idx4[cy * 2 + cx] = (long)(yi * 64 + xi) * 48;
                }
            }
            // ---- logit: dot per corner, then weight ----
            float sh = 0.f;
#pragma unroll
            for (int c = 0; c < 4; ++c) {
                const float4* kc = (const float4*)(cb + idx4[c] + h12);
                float4 k0 = kc[0], k1 = kc[1], k2 = kc[2];
                float d = qv[0]*k0.x + qv[1]*k0.y + qv[2]*k0.z + qv[3]*k0.w
                        + qv[4]*k1.x + qv[5]*k1.y + qv[6]*k1.z + qv[7]*k1.w
                        + qv[8]*k2.x + qv[9]*k2.y + qv[10]*k2.z + qv[11]*k2.w;
                sh = fmaf(w4[c], d, sh);
            }
            float s = sh + __shfl_xor(sh, 1);
            // ---- online softmax ----
            float mn = fmaxf(m, s);
            float corr = __expf(m - mn);
            float p = __expf(s - mn);
            l = l * corr + p;
            m = mn;
            // ---- V sample + accumulate ----
            float vs[12];
#pragma unroll
            for (int d = 0; d < 12; ++d) vs[d] = 0.f;
#pragma unroll
            for (int c = 0; c < 4; ++c) {
                const float4* vc = (const float4*)(cb + idx4[c] + 24 + h12);
                float4 v0 = vc[0], v1 = vc[1], v2 = vc[2];
                float w = w4[c];
                vs[0] = fmaf(w, v0.x, vs[0]);  vs[1] = fmaf(w, v0.y, vs[1]);
                vs[2] = fmaf(w, v0.z, vs[2]);  vs[3] = fmaf(w, v0.w, vs[3]);
                vs[4] = fmaf(w, v1.x, vs[4]);  vs[5] = fmaf(w, v1.y, vs[5]);
                vs[6] = fmaf(w, v1.z, vs[6]);  vs[7] = fmaf(w, v1.w, vs[7]);
                vs[8] = fmaf(w, v2.x, vs[8]);  vs[9] = fmaf(w, v2.y, vs[9]);
                vs[10] = fmaf(w, v2.z, vs[10]); vs[11] = fmaf(w, v2.w, vs[11]);
            }
#pragma unroll
            for (int d = 0; d < 12; ++d)
                outv[d] = fmaf(outv[d], corr, p * vs[d]);
        }
    }
    float inv = 1.f / l;
#pragma unroll
    for (int d = 0; d < 12; ++d)
        o[((long)b * 288 + g * 24 + h12 + d) * AREA + a] = outv[d] * inv;
}

extern "C" void kernel_launch(void* const* d_in, const int* in_sizes, int n_in,
                              void* d_out, int out_size, void* d_ws, size_t ws_size,
                              hipStream_t stream) {
    const float* q      = (const float*)d_in[0];
    const float* k      = (const float*)d_in[1];
    const float* v      = (const float*)d_in[2];
    const float* offset = (const float*)d_in[3];
    const float* Wq     = (const float*)d_in[4];
    const float* bq     = (const float*)d_in[5];
    const float* Wk     = (const float*)d_in[6];
    const float* bk     = (const float*)d_in[7];
    const float* Wv     = (const float*)d_in[8];
    const float* bv     = (const float*)d_in[9];
    const float* W1     = (const float*)d_in[10];
    const float* b1     = (const float*)d_in[11];
    const float* W2     = (const float*)d_in[12];
    const float* b2     = (const float*)d_in[13];
    float* out = (float*)d_out;
    float* ws  = (float*)d_ws;

    float* qp_t = ws;                      // B*12*A*24   = 2,359,296 floats
    float* kv_t = ws + 2359296;            // B*2*12*A*48 = 9,437,184 floats
    float* x1   = ws + 2359296;            // aliases kv_t after attention (2*576*A)

    dim3 blk(256);
    // q projection -> qp_t (gather-major, pstr=24):  8 x-blocks (P=2)
    proj_kernel<24, 2, false, false, true><<<dim3(8, 12, 2), blk, 0, stream>>>(
        q, Wq, bq, qp_t, nullptr, 288, 288L * AREA, 0, 24, 0);
    // k projection -> kv_t[..., 0:24]
    proj_kernel<24, 2, false, false, true><<<dim3(8, 12, 4), blk, 0, stream>>>(
        k, Wk, bk, kv_t, nullptr, 288, 288L * AREA, 0, 48, 0);
    // v projection -> kv_t[..., 24:48]
    proj_kernel<24, 2, false, false, true><<<dim3(8, 12, 4), blk, 0, stream>>>(
        v, Wv, bv, kv_t, nullptr, 288, 288L * AREA, 0, 48, 24);
    // deformable attention -> out ("o")
    deform_attn_kernel<<<dim3(768), blk, 0, stream>>>(qp_t, kv_t, offset, out);
    // FFN layer 1: out(288) -> x1(576) channel-major, GELU
    proj_kernel<24, 2, true, false, false><<<dim3(8, 24, 2), blk, 0, stream>>>(
        out, W1, b1, x1, nullptr, 288, 288L * AREA, 576L * AREA, 0, 0);
    // FFN layer 2: x1(576) -> out(288) + residual o (in-place, same element)
    proj_kernel<24, 2, false, true, false><<<dim3(8, 12, 2), blk, 0, stream>>>(
        x1, W2, b2, out, out, 576, 576L * AREA, 288L * AREA, 0, 0);
}

// Round 5
// 320.921 us; speedup vs baseline: 2.5850x; 2.1575x over previous
//
#include <hip/hip_runtime.h>

#define AREA 4096

__device__ __forceinline__ unsigned bf16_rn(float x) {
    unsigned u = __builtin_bit_cast(unsigned, x);
    u += 0x7fffu + ((u >> 16) & 1u);
    return u >> 16;
}
__device__ __forceinline__ float bflo(unsigned u) { return __builtin_bit_cast(float, u << 16); }
__device__ __forceinline__ float bfhi(unsigned u) { return __builtin_bit_cast(float, u & 0xffff0000u); }

// ---------------- pointwise channel projection -------------------------
// 64-thread (1-wave) blocks: LDS weight staging with NO barriers (DS ops are
// wave-ordered), so global loads pipeline freely across K-steps.
// OUT: 0 = f32 channel-major (+GELU/+RES), 1 = f32 gather-major (qp_t),
//      2 = bf16-packed gather-major (kv_t), voff in uints.
template<bool GELU, bool RES, int OUT>
__global__ __launch_bounds__(64) void proj_kernel(
    const float* __restrict__ in, const float* __restrict__ Wm,
    const float* __restrict__ bias, void* __restrict__ outp,
    const float* __restrict__ res,
    int Cin, long in_stride, long out_n_stride, int voff)
{
    __shared__ float wt[8][24];
    const int tid = threadIdx.x;
    const int a  = blockIdx.x * 64 + tid;
    const int gy = blockIdx.y;
    const int n  = blockIdx.z;
    const float* __restrict__ inp = in + (long)n * in_stride + a;

    float acc[24];
#pragma unroll
    for (int i = 0; i < 24; ++i) acc[i] = 0.f;

    for (int c0 = 0; c0 < Cin; c0 += 8) {
        // stage 8x24 weights (wave-ordered DS; no barrier needed, 1 wave/block)
#pragma unroll
        for (int j = 0; j < 3; ++j) {
            int idx = tid + 64 * j;
            int cc = idx & 7, oo = idx >> 3;
            wt[cc][oo] = Wm[(long)(gy * 24 + oo) * Cin + c0 + cc];
        }
        float xv[8];
#pragma unroll
        for (int cc = 0; cc < 8; ++cc) xv[cc] = inp[(long)(c0 + cc) * AREA];
#pragma unroll
        for (int cc = 0; cc < 8; ++cc) {
            const float4* wr = (const float4*)&wt[cc][0];   // broadcast reads
            float4 w0 = wr[0], w1 = wr[1], w2 = wr[2], w3 = wr[3], w4_ = wr[4], w5 = wr[5];
            float x = xv[cc];
            acc[0]=fmaf(w0.x,x,acc[0]);  acc[1]=fmaf(w0.y,x,acc[1]);
            acc[2]=fmaf(w0.z,x,acc[2]);  acc[3]=fmaf(w0.w,x,acc[3]);
            acc[4]=fmaf(w1.x,x,acc[4]);  acc[5]=fmaf(w1.y,x,acc[5]);
            acc[6]=fmaf(w1.z,x,acc[6]);  acc[7]=fmaf(w1.w,x,acc[7]);
            acc[8]=fmaf(w2.x,x,acc[8]);  acc[9]=fmaf(w2.y,x,acc[9]);
            acc[10]=fmaf(w2.z,x,acc[10]); acc[11]=fmaf(w2.w,x,acc[11]);
            acc[12]=fmaf(w3.x,x,acc[12]); acc[13]=fmaf(w3.y,x,acc[13]);
            acc[14]=fmaf(w3.z,x,acc[14]); acc[15]=fmaf(w3.w,x,acc[15]);
            acc[16]=fmaf(w4_.x,x,acc[16]); acc[17]=fmaf(w4_.y,x,acc[17]);
            acc[18]=fmaf(w4_.z,x,acc[18]); acc[19]=fmaf(w4_.w,x,acc[19]);
            acc[20]=fmaf(w5.x,x,acc[20]); acc[21]=fmaf(w5.y,x,acc[21]);
            acc[22]=fmaf(w5.z,x,acc[22]); acc[23]=fmaf(w5.w,x,acc[23]);
        }
    }

    if (OUT == 1) {
        float* fb = (float*)outp + ((long)(n * 12 + gy) * AREA + a) * 24;
#pragma unroll
        for (int oo = 0; oo < 24; ++oo) fb[oo] = acc[oo] + bias[gy * 24 + oo];
    } else if (OUT == 2) {
        unsigned* ub = (unsigned*)outp + ((long)(n * 12 + gy) * AREA + a) * 24 + voff;
#pragma unroll
        for (int j = 0; j < 12; ++j) {
            float e = acc[2 * j]     + bias[gy * 24 + 2 * j];
            float f = acc[2 * j + 1] + bias[gy * 24 + 2 * j + 1];
            ub[j] = bf16_rn(e) | (bf16_rn(f) << 16);
        }
    } else {
        float* fb = (float*)outp;
        const long obase = (long)n * out_n_stride + a;
#pragma unroll
        for (int oo = 0; oo < 24; ++oo) {
            float vr = acc[oo] + bias[gy * 24 + oo];
            if (GELU) vr = 0.5f * vr * (1.f + erff(vr * 0.70710678118654752f));
            long addr = obase + (long)(gy * 24 + oo) * AREA;
            if (RES) vr += res[addr];
            fb[addr] = vr;
        }
    }
}

// ---------------- deformable attention ---------------------------------
// qp_t: (B*12, A, 24) f32    kv: (B*CLIP*12, A, 24 uints = 48 bf16) K then V
// Lane pair per site: even lane (role 0) gathers K + dot; odd lane (role 1)
// gathers V + weighted sum; logit shared via shfl_xor. 24 x 16B reqs/site-sample.
__global__ __launch_bounds__(256) void deform_attn_kernel(
    const float* __restrict__ qp, const unsigned* __restrict__ kv,
    const float* __restrict__ offs, float* __restrict__ o)
{
    const int t = blockIdx.x * 256 + threadIdx.x;
    const int role = t & 1;
    const int site = t >> 1;                 // (b*12 + g)*A + a
    const int a = site & (AREA - 1);
    const int g = (site >> 12) % 12;
    const int b = site / (12 * AREA);
    const int py = a >> 6, px = a & 63;
    const float scale = 0.20412414523193150818f;   // 1/sqrt(24)

    float qv[24];
    {
        const float4* qb = (const float4*)(qp + (long)site * 24);
#pragma unroll
        for (int i = 0; i < 6; ++i) {
            float4 qq = qb[i];
            qv[4*i+0] = qq.x * scale; qv[4*i+1] = qq.y * scale;
            qv[4*i+2] = qq.z * scale; qv[4*i+3] = qq.w * scale;
        }
    }

    float m = -1e30f, l = 0.f;
    float outv[24];
#pragma unroll
    for (int d = 0; d < 24; ++d) outv[d] = 0.f;

    for (int clip = 0; clip < 2; ++clip) {
        const unsigned* __restrict__ cb =
            kv + (long)((b * 2 + clip) * 12 + g) * AREA * 24 + role * 12;
        const float* __restrict__ obase =
            offs + ((long)b * 432 + (clip * 12 + g) * 18) * AREA;
#pragma unroll 1
        for (int k = 0; k < 9; ++k) {
            float oy = obase[(long)(2 * k) * AREA + a];
            float ox = obase[(long)(2 * k + 1) * AREA + a];
            int ky = k / 3, kx = k - ky * 3;
            float ys = (float)(py + ky - 1) + oy;
            float xs_ = (float)(px + kx - 1) + ox;
            float y0f = floorf(ys), x0f = floorf(xs_);
            float dy = ys - y0f, dx = xs_ - x0f;
            float wy[2] = {1.f - dy, dy};
            float wx[2] = {1.f - dx, dx};
            long  idx4[4];
            float w4[4];
#pragma unroll
            for (int cy = 0; cy < 2; ++cy) {
                float yc = y0f + (float)cy;
                bool vy = (yc >= 0.f) && (yc <= 63.f);
                int yi = (int)fminf(fmaxf(yc, 0.f), 63.f);
#pragma unroll
                for (int cx = 0; cx < 2; ++cx) {
                    float xc = x0f + (float)cx;
                    bool vx = (xc >= 0.f) && (xc <= 63.f);
                    int xi = (int)fminf(fmaxf(xc, 0.f), 63.f);
                    w4[cy * 2 + cx] = wy[cy] * wx[cx] * ((vy && vx) ? 1.f : 0.f);
                    idx4[cy * 2 + cx] = (long)(yi * 64 + xi) * 24;
                }
            }
            float xs[24];
#pragma unroll
            for (int j = 0; j < 24; ++j) xs[j] = 0.f;
            float sh = 0.f;
#pragma unroll
            for (int c = 0; c < 4; ++c) {
                const uint4* pc = (const uint4*)(cb + idx4[c]);
                uint4 u0 = pc[0], u1 = pc[1], u2 = pc[2];
                unsigned uu[12] = {u0.x, u0.y, u0.z, u0.w,
                                   u1.x, u1.y, u1.z, u1.w,
                                   u2.x, u2.y, u2.z, u2.w};
                float w = w4[c];
                float d = 0.f;
#pragma unroll
                for (int j = 0; j < 12; ++j) {
                    float lo = bflo(uu[j]), hi = bfhi(uu[j]);
                    d = fmaf(qv[2 * j], lo, d);
                    d = fmaf(qv[2 * j + 1], hi, d);
                    xs[2 * j]     = fmaf(w, lo, xs[2 * j]);
                    xs[2 * j + 1] = fmaf(w, hi, xs[2 * j + 1]);
                }
                sh = fmaf(w, d, sh);
            }
            float sx = __shfl_xor(sh, 1);
            float s = role ? sx : sh;          // even lane's full K-dot
            float mn = fmaxf(m, s);
            float corr = __expf(m - mn);
            float p = __expf(s - mn);
            l = l * corr + p;
            m = mn;
#pragma unroll
            for (int j = 0; j < 24; ++j)
                outv[j] = fmaf(outv[j], corr, p * xs[j]);
        }
    }
    if (role) {
        float inv = 1.f / l;
#pragma unroll
        for (int d = 0; d < 24; ++d)
            o[((long)b * 288 + g * 24 + d) * AREA + a] = outv[d] * inv;
    }
}

extern "C" void kernel_launch(void* const* d_in, const int* in_sizes, int n_in,
                              void* d_out, int out_size, void* d_ws, size_t ws_size,
                              hipStream_t stream) {
    const float* q      = (const float*)d_in[0];
    const float* k      = (const float*)d_in[1];
    const float* v      = (const float*)d_in[2];
    const float* offset = (const float*)d_in[3];
    const float* Wq     = (const float*)d_in[4];
    const float* bq     = (const float*)d_in[5];
    const float* Wk     = (const float*)d_in[6];
    const float* bk     = (const float*)d_in[7];
    const float* Wv     = (const float*)d_in[8];
    const float* bv     = (const float*)d_in[9];
    const float* W1     = (const float*)d_in[10];
    const float* b1     = (const float*)d_in[11];
    const float* W2     = (const float*)d_in[12];
    const float* b2     = (const float*)d_in[13];
    float* out = (float*)d_out;
    float* ws  = (float*)d_ws;

    float*    qp_t = ws;                          // 2,359,296 f32 (9.4 MB)
    unsigned* kv_u = (unsigned*)(ws + 2359296);   // 4,718,592 uints (18.9 MB)
    float*    x1   = ws + 2359296;                // aliases kv after attn (18.9 MB)

    // q projection -> qp_t (f32 gather-major)
    proj_kernel<false, false, 1><<<dim3(64, 12, 2), dim3(64), 0, stream>>>(
        q, Wq, bq, qp_t, nullptr, 288, 288L * AREA, 0, 0);
    // k projection -> kv_u[..., uints 0:12]  (bf16)
    proj_kernel<false, false, 2><<<dim3(64, 12, 4), dim3(64), 0, stream>>>(
        k, Wk, bk, kv_u, nullptr, 288, 288L * AREA, 0, 0);
    // v projection -> kv_u[..., uints 12:24] (bf16)
    proj_kernel<false, false, 2><<<dim3(64, 12, 4), dim3(64), 0, stream>>>(
        v, Wv, bv, kv_u, nullptr, 288, 288L * AREA, 0, 12);
    // deformable attention -> out ("o"): 196608 threads
    deform_attn_kernel<<<dim3(768), dim3(256), 0, stream>>>(qp_t, kv_u, offset, out);
    // FFN layer 1: out(288) -> x1(576) channel-major, GELU
    proj_kernel<true, false, 0><<<dim3(64, 24, 2), dim3(64), 0, stream>>>(
        out, W1, b1, x1, nullptr, 288, 288L * AREA, 576L * AREA, 0);
    // FFN layer 2: x1(576) -> out(288) + residual o (in-place, same element)
    proj_kernel<false, true, 0><<<dim3(64, 12, 2), dim3(64), 0, stream>>>(
        x1, W2, b2, out, out, 576, 576L * AREA, 288L * AREA, 0);
}

// Round 6
// 153.297 us; speedup vs baseline: 5.4117x; 2.0935x over previous
//
#include <hip/hip_runtime.h>

#define AREA 4096

typedef short short8 __attribute__((ext_vector_type(8)));
typedef float f32x4 __attribute__((ext_vector_type(4)));

__device__ __forceinline__ unsigned bf16_rn(float x) {
    unsigned u = __builtin_bit_cast(unsigned, x);
    u += 0x7fffu + ((u >> 16) & 1u);
    return u >> 16;
}
__device__ __forceinline__ float bflo(unsigned u) { return __builtin_bit_cast(float, u << 16); }
__device__ __forceinline__ float bfhi(unsigned u) { return __builtin_bit_cast(float, u & 0xffff0000u); }
__device__ __forceinline__ float gelu_f(float x) {
    return 0.5f * x * (1.f + erff(x * 0.70710678118654752f));
}

// ---- pack W (f32 row-major [O][Cin]) into A-fragment tiles -------------
// Frag tile (ot, ks): lane l holds W[ot*16+(l&15)][ks*32+(l>>4)*8 + j], j=0..7
// packed as 4 u32 (bf16 pairs). Stored as uint4 at [(ot*KS+ks)*64 + l].
__global__ __launch_bounds__(256) void pack_w_kernel(
    const float* __restrict__ Wq, const float* __restrict__ Wk,
    const float* __restrict__ Wv, const float* __restrict__ W1,
    const float* __restrict__ W2, uint4* __restrict__ wp_base,
    int off_q, int off_k, int off_v, int off_1, int off_2)
{
    const float* W; int Cin, OT, KS; uint4* dst;
    switch (blockIdx.y) {
        case 0: W = Wq; Cin = 288; OT = 18; KS = 9;  dst = wp_base + off_q; break;
        case 1: W = Wk; Cin = 288; OT = 18; KS = 9;  dst = wp_base + off_k; break;
        case 2: W = Wv; Cin = 288; OT = 18; KS = 9;  dst = wp_base + off_v; break;
        case 3: W = W1; Cin = 288; OT = 36; KS = 9;  dst = wp_base + off_1; break;
        default:W = W2; Cin = 576; OT = 18; KS = 18; dst = wp_base + off_2; break;
    }
    int wt = blockIdx.x * 4 + (threadIdx.x >> 6);
    if (wt >= OT * KS) return;
    int lane = threadIdx.x & 63;
    int ot = wt / KS, ks = wt - ot * KS;
    int o = ot * 16 + (lane & 15);
    int c0 = ks * 32 + ((lane >> 4) << 3);
    const float4* wr = (const float4*)(W + (long)o * Cin + c0);
    float4 f0 = wr[0], f1 = wr[1];
    uint4 u;
    u.x = bf16_rn(f0.x) | (bf16_rn(f0.y) << 16);
    u.y = bf16_rn(f0.z) | (bf16_rn(f0.w) << 16);
    u.z = bf16_rn(f1.x) | (bf16_rn(f1.y) << 16);
    u.w = bf16_rn(f1.z) | (bf16_rn(f1.w) << 16);
    dst[(long)wt * 64 + lane] = u;
}

// ---- transpose inputs: f32 [n][288][A] -> bf16-packed [n*A][144 u32] ---
__global__ __launch_bounds__(256) void tp_kernel(
    const float* __restrict__ q, const float* __restrict__ k,
    const float* __restrict__ v, unsigned* __restrict__ xq,
    unsigned* __restrict__ xk, unsigned* __restrict__ xv)
{
    const float* src; unsigned* dst; int nimg;
    switch (blockIdx.y) {
        case 0: src = q; dst = xq; nimg = 2; break;
        case 1: src = k; dst = xk; nimg = 4; break;
        default:src = v; dst = xv; nimg = 4; break;
    }
    int idx = blockIdx.x * 256 + threadIdx.x;
    if (idx >= nimg * AREA * 36) return;
    int a = idx & (AREA - 1);
    int rest = idx >> 12;
    int oct = rest % 36;
    int n = rest / 36;
    const float* s = src + ((long)n * 288 + oct * 8) * AREA + a;
    uint4 u;
    u.x = bf16_rn(s[0])        | (bf16_rn(s[AREA])     << 16);
    u.y = bf16_rn(s[2 * AREA]) | (bf16_rn(s[3 * AREA]) << 16);
    u.z = bf16_rn(s[4 * AREA]) | (bf16_rn(s[5 * AREA]) << 16);
    u.w = bf16_rn(s[6 * AREA]) | (bf16_rn(s[7 * AREA]) << 16);
    *(uint4*)(dst + ((long)n * AREA + a) * 144 + oct * 4) = u;
}

// ---- MFMA projection ---------------------------------------------------
// C[o,p] = sum_c W[o,c] X[c,p].  B read from pixel-major packed bf16 Xt
// (row stride RSu u32).  Wave: 32 o x 64 p (2 A-frags x 4 B-frags, 8 MFMA/ks).
// Block: 4 waves side-by-side in p (256 p).  No LDS, no barriers.
// OUT: 0 = f32 chan-major + res (FFN2)   1 = f32 [site][288] (qp)
//      2 = bf16 kv group-major, +voff    3 = bf16 [site][288 u32] + GELU (x1)
template<int OUT>
__global__ __launch_bounds__(256) void proj_mfma(
    const unsigned* __restrict__ Xt, const uint4* __restrict__ Wp,
    const float* __restrict__ bias, void* __restrict__ outp,
    const float* __restrict__ res, int KS, int RSu, int voff)
{
    const int tid = threadIdx.x;
    const int lane = tid & 63;
    const int w = tid >> 6;
    const int n = blockIdx.z;
    const int ot0 = blockIdx.y * 2;
    const int pw = blockIdx.x * 256 + w * 64;
    const int lcol = lane & 15;
    const int lrow = lane >> 4;

    const uint4* xrow[4];
#pragma unroll
    for (int s = 0; s < 4; ++s)
        xrow[s] = (const uint4*)(Xt + ((long)n * AREA + pw + s * 16 + lcol) * RSu);
    const uint4* wa0 = Wp + (long)ot0 * KS * 64 + lane;
    const uint4* wa1 = Wp + (long)(ot0 + 1) * KS * 64 + lane;

    f32x4 acc[2][4];
#pragma unroll
    for (int m = 0; m < 2; ++m)
#pragma unroll
        for (int s = 0; s < 4; ++s) acc[m][s] = (f32x4){0.f, 0.f, 0.f, 0.f};

    for (int ks = 0; ks < KS; ++ks) {
        uint4 a0 = wa0[(long)ks * 64];
        uint4 a1 = wa1[(long)ks * 64];
        uint4 b[4];
#pragma unroll
        for (int s = 0; s < 4; ++s) b[s] = xrow[s][ks * 4 + lrow];
        short8 A0 = __builtin_bit_cast(short8, a0);
        short8 A1 = __builtin_bit_cast(short8, a1);
#pragma unroll
        for (int s = 0; s < 4; ++s) {
            short8 B = __builtin_bit_cast(short8, b[s]);
            acc[0][s] = __builtin_amdgcn_mfma_f32_16x16x32_bf16(A0, B, acc[0][s], 0, 0, 0);
            acc[1][s] = __builtin_amdgcn_mfma_f32_16x16x32_bf16(A1, B, acc[1][s], 0, 0, 0);
        }
    }

#pragma unroll
    for (int m = 0; m < 2; ++m) {
        const int obase = (ot0 + m) * 16 + lrow * 4;
        const float b0 = bias[obase], b1 = bias[obase + 1];
        const float b2 = bias[obase + 2], b3 = bias[obase + 3];
#pragma unroll
        for (int s = 0; s < 4; ++s) {
            const int pcol = pw + s * 16 + lcol;
            f32x4 a = acc[m][s];
            float v0 = a[0] + b0, v1 = a[1] + b1, v2 = a[2] + b2, v3 = a[3] + b3;
            if (OUT == 1) {
                float4 st = {v0, v1, v2, v3};
                *(float4*)((float*)outp + ((long)n * AREA + pcol) * 288 + obase) = st;
            } else if (OUT == 2) {
                int g = obase / 24, d0 = obase % 24;
                unsigned* ub = (unsigned*)outp +
                    ((long)(n * 12 + g) * AREA + pcol) * 24 + voff + (d0 >> 1);
                uint2 st;
                st.x = bf16_rn(v0) | (bf16_rn(v1) << 16);
                st.y = bf16_rn(v2) | (bf16_rn(v3) << 16);
                *(uint2*)ub = st;
            } else if (OUT == 3) {
                v0 = gelu_f(v0); v1 = gelu_f(v1); v2 = gelu_f(v2); v3 = gelu_f(v3);
                uint2 st;
                st.x = bf16_rn(v0) | (bf16_rn(v1) << 16);
                st.y = bf16_rn(v2) | (bf16_rn(v3) << 16);
                *(uint2*)((unsigned*)outp + ((long)n * AREA + pcol) * 288 + (obase >> 1)) = st;
            } else {
                float* fb = (float*)outp;
                float vals[4] = {v0, v1, v2, v3};
#pragma unroll
                for (int r = 0; r < 4; ++r) {
                    long addr = ((long)n * 288 + obase + r) * AREA + pcol;
                    fb[addr] = vals[r] + res[addr];
                }
            }
        }
    }
}

// ---------------- deformable attention ---------------------------------
// qp: f32 [b*A + a][288]    kv: bf16-packed (B*CLIP*12, A, 24 u32) K|V
// o:  f32 chan-major d_out  o_t: bf16-packed [b*A + a][144 u32] (FFN1 input)
__global__ __launch_bounds__(256) void deform_attn_kernel(
    const float* __restrict__ qp, const unsigned* __restrict__ kv,
    const float* __restrict__ offs, float* __restrict__ o,
    unsigned* __restrict__ ot)
{
    const int t = blockIdx.x * 256 + threadIdx.x;
    const int role = t & 1;
    const int site = t >> 1;                 // (b*12 + g)*A + a
    const int a = site & (AREA - 1);
    const int g = (site >> 12) % 12;
    const int b = site / (12 * AREA);
    const int py = a >> 6, px = a & 63;
    const float scale = 0.20412414523193150818f;   // 1/sqrt(24)

    float qv[24];
    {
        const float4* qb = (const float4*)(qp + ((long)b * AREA + a) * 288 + g * 24);
#pragma unroll
        for (int i = 0; i < 6; ++i) {
            float4 qq = qb[i];
            qv[4*i+0] = qq.x * scale; qv[4*i+1] = qq.y * scale;
            qv[4*i+2] = qq.z * scale; qv[4*i+3] = qq.w * scale;
        }
    }

    float m = -1e30f, l = 0.f;
    float outv[24];
#pragma unroll
    for (int d = 0; d < 24; ++d) outv[d] = 0.f;

    for (int clip = 0; clip < 2; ++clip) {
        const unsigned* __restrict__ cb =
            kv + (long)((b * 2 + clip) * 12 + g) * AREA * 24 + role * 12;
        const float* __restrict__ obase =
            offs + ((long)b * 432 + (clip * 12 + g) * 18) * AREA;
#pragma unroll 1
        for (int k = 0; k < 9; ++k) {
            float oy = obase[(long)(2 * k) * AREA + a];
            float ox = obase[(long)(2 * k + 1) * AREA + a];
            int ky = k / 3, kx = k - ky * 3;
            float ys = (float)(py + ky - 1) + oy;
            float xs_ = (float)(px + kx - 1) + ox;
            float y0f = floorf(ys), x0f = floorf(xs_);
            float dy = ys - y0f, dx = xs_ - x0f;
            float wy[2] = {1.f - dy, dy};
            float wx[2] = {1.f - dx, dx};
            long  idx4[4];
            float w4[4];
#pragma unroll
            for (int cy = 0; cy < 2; ++cy) {
                float yc = y0f + (float)cy;
                bool vy = (yc >= 0.f) && (yc <= 63.f);
                int yi = (int)fminf(fmaxf(yc, 0.f), 63.f);
#pragma unroll
                for (int cx = 0; cx < 2; ++cx) {
                    float xc = x0f + (float)cx;
                    bool vx = (xc >= 0.f) && (xc <= 63.f);
                    int xi = (int)fminf(fmaxf(xc, 0.f), 63.f);
                    w4[cy * 2 + cx] = wy[cy] * wx[cx] * ((vy && vx) ? 1.f : 0.f);
                    idx4[cy * 2 + cx] = (long)(yi * 64 + xi) * 24;
                }
            }
            float xs[24];
#pragma unroll
            for (int j = 0; j < 24; ++j) xs[j] = 0.f;
            float sh = 0.f;
#pragma unroll
            for (int c = 0; c < 4; ++c) {
                const uint4* pc = (const uint4*)(cb + idx4[c]);
                uint4 u0 = pc[0], u1 = pc[1], u2 = pc[2];
                unsigned uu[12] = {u0.x, u0.y, u0.z, u0.w,
                                   u1.x, u1.y, u1.z, u1.w,
                                   u2.x, u2.y, u2.z, u2.w};
                float w = w4[c];
                float d = 0.f;
#pragma unroll
                for (int j = 0; j < 12; ++j) {
                    float lo = bflo(uu[j]), hi = bfhi(uu[j]);
                    d = fmaf(qv[2 * j], lo, d);
                    d = fmaf(qv[2 * j + 1], hi, d);
                    xs[2 * j]     = fmaf(w, lo, xs[2 * j]);
                    xs[2 * j + 1] = fmaf(w, hi, xs[2 * j + 1]);
                }
                sh = fmaf(w, d, sh);
            }
            float sx = __shfl_xor(sh, 1);
            float s = role ? sx : sh;          // even lane's full K-dot
            float mn = fmaxf(m, s);
            float corr = __expf(m - mn);
            float p = __expf(s - mn);
            l = l * corr + p;
            m = mn;
#pragma unroll
            for (int j = 0; j < 24; ++j)
                outv[j] = fmaf(outv[j], corr, p * xs[j]);
        }
    }
    if (role) {
        float inv = 1.f / l;
        float ov[24];
#pragma unroll
        for (int d = 0; d < 24; ++d) {
            ov[d] = outv[d] * inv;
            o[((long)b * 288 + g * 24 + d) * AREA + a] = ov[d];
        }
        unsigned* tb = ot + ((long)b * AREA + a) * 144 + g * 12;
        uint4 s0, s1, s2;
        s0.x = bf16_rn(ov[0])  | (bf16_rn(ov[1])  << 16);
        s0.y = bf16_rn(ov[2])  | (bf16_rn(ov[3])  << 16);
        s0.z = bf16_rn(ov[4])  | (bf16_rn(ov[5])  << 16);
        s0.w = bf16_rn(ov[6])  | (bf16_rn(ov[7])  << 16);
        s1.x = bf16_rn(ov[8])  | (bf16_rn(ov[9])  << 16);
        s1.y = bf16_rn(ov[10]) | (bf16_rn(ov[11]) << 16);
        s1.z = bf16_rn(ov[12]) | (bf16_rn(ov[13]) << 16);
        s1.w = bf16_rn(ov[14]) | (bf16_rn(ov[15]) << 16);
        s2.x = bf16_rn(ov[16]) | (bf16_rn(ov[17]) << 16);
        s2.y = bf16_rn(ov[18]) | (bf16_rn(ov[19]) << 16);
        s2.z = bf16_rn(ov[20]) | (bf16_rn(ov[21]) << 16);
        s2.w = bf16_rn(ov[22]) | (bf16_rn(ov[23]) << 16);
        ((uint4*)tb)[0] = s0; ((uint4*)tb)[1] = s1; ((uint4*)tb)[2] = s2;
    }
}

extern "C" void kernel_launch(void* const* d_in, const int* in_sizes, int n_in,
                              void* d_out, int out_size, void* d_ws, size_t ws_size,
                              hipStream_t stream) {
    const float* q      = (const float*)d_in[0];
    const float* k      = (const float*)d_in[1];
    const float* v      = (const float*)d_in[2];
    const float* offset = (const float*)d_in[3];
    const float* Wq     = (const float*)d_in[4];
    const float* bq     = (const float*)d_in[5];
    const float* Wk     = (const float*)d_in[6];
    const float* bk     = (const float*)d_in[7];
    const float* Wv     = (const float*)d_in[8];
    const float* bv     = (const float*)d_in[9];
    const float* W1     = (const float*)d_in[10];
    const float* b1     = (const float*)d_in[11];
    const float* W2     = (const float*)d_in[12];
    const float* b2     = (const float*)d_in[13];
    float* out = (float*)d_out;
    float* ws  = (float*)d_ws;

    // ws layout (f32/u32 units)
    float*    qp   = ws;                               // 2,359,296 f32
    unsigned* kv_u = (unsigned*)(ws + 2359296);        // 4,718,592 u32
    unsigned* xq   = (unsigned*)(ws + 7077888);        // 1,179,648 u32
    unsigned* xk   = (unsigned*)(ws + 8257536);        // 2,359,296 u32 (x1 aliases)
    unsigned* xv   = (unsigned*)(ws + 10616832);       // 2,359,296 u32 (o_t aliases)
    uint4*    wp   = (uint4*)(ws + 12976128);          // 290,304 u32 total
    unsigned* x1   = xk;
    unsigned* o_t  = xv;
    const int OFF_Q = 0, OFF_K = 162 * 64, OFF_V = 324 * 64;
    const int OFF_1 = 486 * 64, OFF_2 = 810 * 64;      // uint4 offsets

    // 1) pack weights (5 matrices, one launch)
    pack_w_kernel<<<dim3(81, 5), dim3(256), 0, stream>>>(
        Wq, Wk, Wv, W1, W2, wp, OFF_Q, OFF_K, OFF_V, OFF_1, OFF_2);
    // 2) transpose q/k/v inputs to pixel-major bf16
    tp_kernel<<<dim3(2304, 3), dim3(256), 0, stream>>>(q, k, v, xq, xk, xv);
    // 3) projections (MFMA)
    proj_mfma<1><<<dim3(16, 9, 2), dim3(256), 0, stream>>>(
        xq, wp + OFF_Q, bq, qp, nullptr, 9, 144, 0);
    proj_mfma<2><<<dim3(16, 9, 4), dim3(256), 0, stream>>>(
        xk, wp + OFF_K, bk, kv_u, nullptr, 9, 144, 0);
    proj_mfma<2><<<dim3(16, 9, 4), dim3(256), 0, stream>>>(
        xv, wp + OFF_V, bv, kv_u, nullptr, 9, 144, 12);
    // 4) deformable attention -> d_out (f32) + o_t (bf16 pixel-major)
    deform_attn_kernel<<<dim3(768), dim3(256), 0, stream>>>(
        qp, kv_u, offset, out, o_t);
    // 5) FFN1: o_t(288) -> x1(576) bf16 pixel-major, GELU
    proj_mfma<3><<<dim3(16, 18, 2), dim3(256), 0, stream>>>(
        o_t, wp + OFF_1, b1, x1, nullptr, 9, 144, 0);
    // 6) FFN2: x1(576) -> d_out f32 chan-major + residual o
    proj_mfma<0><<<dim3(16, 9, 2), dim3(256), 0, stream>>>(
        x1, wp + OFF_2, b2, out, out, 18, 288, 0);
}